// Round 1
// baseline (338.277 us; speedup 1.0000x reference)
//
#include <hip/hip_runtime.h>
#include <hip/hip_bf16.h>

#define NT 8192      // tokens
#define DM 512       // d_model
#define DF 1024      // d_ff
#define NE 8         // experts
#define MAXROWS (NT*2)

typedef __bf16 bf16_8 __attribute__((ext_vector_type(8)));
typedef float  f32_4  __attribute__((ext_vector_type(4)));
typedef unsigned short us8 __attribute__((ext_vector_type(8)));

__device__ inline unsigned short f2bf(float f) {
    unsigned int u = __float_as_uint(f);
    u = u + 0x7fffu + ((u >> 16) & 1u);   // RNE
    return (unsigned short)(u >> 16);
}

__device__ inline bf16_8 as_bf(us8 v) { return __builtin_bit_cast(bf16_8, v); }

// ---------------- cast f32 -> bf16 (4 elems/thread) ----------------
__global__ __launch_bounds__(256) void cast_kernel(const float* __restrict__ in,
                                                   unsigned short* __restrict__ out,
                                                   int n4) {
    int i = blockIdx.x * 256 + threadIdx.x;
    if (i >= n4) return;
    float4 v = ((const float4*)in)[i];
    ushort4 o;
    o.x = f2bf(v.x); o.y = f2bf(v.y); o.z = f2bf(v.z); o.w = f2bf(v.w);
    ((ushort4*)out)[i] = o;
}

// ---------------- router: f32 logits, top-2, gates, expert lists ----------------
__global__ __launch_bounds__(256) void router_kernel(const float* __restrict__ x,
                                                     const float* __restrict__ wr,
                                                     int* __restrict__ counts,
                                                     int* __restrict__ token_list,
                                                     float* __restrict__ gate_list) {
    const int wid = threadIdx.x >> 6;
    const int lane = threadIdx.x & 63;
    const int t = blockIdx.x * 4 + wid;

    const float4* xrow = (const float4*)(x + (size_t)t * DM);
    float4 xv0 = xrow[lane * 2];
    float4 xv1 = xrow[lane * 2 + 1];

    float logit[NE];
#pragma unroll
    for (int e = 0; e < NE; ++e) {
        const float4* wrow = (const float4*)(wr + (size_t)e * DM);
        float4 w0 = wrow[lane * 2];
        float4 w1v = wrow[lane * 2 + 1];
        float s = xv0.x * w0.x + xv0.y * w0.y + xv0.z * w0.z + xv0.w * w0.w
                + xv1.x * w1v.x + xv1.y * w1v.y + xv1.z * w1v.z + xv1.w * w1v.w;
#pragma unroll
        for (int off = 32; off >= 1; off >>= 1) s += __shfl_xor(s, off);
        logit[e] = s;
    }

    if (lane == 0) {
        int i0 = 0; float m0 = logit[0];
#pragma unroll
        for (int e = 1; e < NE; ++e) if (logit[e] > m0) { m0 = logit[e]; i0 = e; }
        int i1 = -1; float m1 = -1e30f;
#pragma unroll
        for (int e = 0; e < NE; ++e) if (e != i0 && logit[e] > m1) { m1 = logit[e]; i1 = e; }
        // gates: renormalized top-2 of softmax == 2-way softmax over (m0, m1)
        float d = expf(m1 - m0);
        float g0 = 1.0f / (1.0f + d);
        float g1 = 1.0f - g0;
        int s0 = atomicAdd(&counts[i0], 1);
        token_list[i0 * NT + s0] = t;
        gate_list[i0 * NT + s0] = g0;
        int s1 = atomicAdd(&counts[i1], 1);
        token_list[i1 * NT + s1] = t;
        gate_list[i1 * NT + s1] = g1;
    }
}

// ---------------- exclusive scan over 8 counts ----------------
__global__ void scan_kernel(const int* __restrict__ counts, int* __restrict__ offsets) {
    if (threadIdx.x == 0) {
        int s = 0;
        for (int e = 0; e < NE; ++e) { offsets[e] = s; s += counts[e]; }
    }
}

// ---------------- fused MoE GEMM (templated on layer) ----------------
// G1: h = silu(gather(x) @ W1[e]^T)   A=x_bf16 [NT][512], B=w1 [NE][1024][512], out h bf16
// G2: out += gate * (h @ W2[e]^T)     A=h [rows][1024],  B=w2 [NE][512][1024], atomicAdd f32
template <bool G1>
__global__ __launch_bounds__(256) void moe_gemm(const unsigned short* __restrict__ Abase,
                                                const unsigned short* __restrict__ Wbase,
                                                unsigned short* __restrict__ h_out,
                                                float* __restrict__ out,
                                                const int* __restrict__ counts,
                                                const int* __restrict__ offsets,
                                                const int* __restrict__ token_list,
                                                const float* __restrict__ gate_list) {
    constexpr int K = G1 ? DM : DF;       // 512 : 1024
    constexpr int NCOLS = G1 ? DF : DM;   // 1024 : 512
    const int e = blockIdx.z;
    const int cnt = counts[e];
    const int row0 = blockIdx.y * 64;
    if (row0 >= cnt) return;
    const int col0 = blockIdx.x * 64;

    __shared__ __align__(16) unsigned short Alds[64][40];
    __shared__ __align__(16) unsigned short Blds[64][40];

    const int tr = threadIdx.x >> 2;   // 0..63 staged row
    const int tc = threadIdx.x & 3;    // 0..3  16B chunk within 32-wide K-step

    // per-thread A row pointer (fixed across K loop), clamped for tail tiles
    int rloc = min(row0 + tr, cnt - 1);
    const unsigned short* Arow;
    if (G1) {
        int tok = token_list[e * NT + rloc];
        Arow = Abase + (size_t)tok * K;
    } else {
        Arow = Abase + (size_t)(offsets[e] + rloc) * K;
    }
    const unsigned short* Brow = Wbase + ((size_t)e * NCOLS + (col0 + tr)) * K;

    const int wid = threadIdx.x >> 6;
    const int lane = threadIdx.x & 63;
    const int wr = wid >> 1, wc = wid & 1;
    const int lrow = lane & 15;
    const int kc = lane >> 4;

    f32_4 acc[2][2];
#pragma unroll
    for (int m = 0; m < 2; ++m)
#pragma unroll
        for (int n = 0; n < 2; ++n) acc[m][n] = (f32_4){0.f, 0.f, 0.f, 0.f};

    for (int k0 = 0; k0 < K; k0 += 32) {
        us8 av = *(const us8*)(Arow + k0 + tc * 8);
        us8 bv = *(const us8*)(Brow + k0 + tc * 8);
        __syncthreads();
        *(us8*)&Alds[tr][tc * 8] = av;
        *(us8*)&Blds[tr][tc * 8] = bv;
        __syncthreads();

        bf16_8 a[2], b[2];
#pragma unroll
        for (int m = 0; m < 2; ++m)
            a[m] = as_bf(*(const us8*)&Alds[wr * 32 + m * 16 + lrow][kc * 8]);
#pragma unroll
        for (int n = 0; n < 2; ++n)
            b[n] = as_bf(*(const us8*)&Blds[wc * 32 + n * 16 + lrow][kc * 8]);
#pragma unroll
        for (int m = 0; m < 2; ++m)
#pragma unroll
            for (int n = 0; n < 2; ++n)
                acc[m][n] = __builtin_amdgcn_mfma_f32_16x16x32_bf16(a[m], b[n], acc[m][n], 0, 0, 0);
    }

    // epilogue: D row = (lane>>4)*4 + q, col = lane&15 within each 16x16 frag
#pragma unroll
    for (int m = 0; m < 2; ++m) {
#pragma unroll
        for (int n = 0; n < 2; ++n) {
#pragma unroll
            for (int q = 0; q < 4; ++q) {
                int lr = wr * 32 + m * 16 + (lane >> 4) * 4 + q;
                int lc = wc * 32 + n * 16 + (lane & 15);
                int r = row0 + lr;
                if (r < cnt) {
                    float v = acc[m][n][q];
                    if (G1) {
                        v = v / (1.0f + expf(-v));  // silu
                        h_out[(size_t)(offsets[e] + r) * DF + col0 + lc] = f2bf(v);
                    } else {
                        float g = gate_list[e * NT + r];
                        int tok = token_list[e * NT + r];
                        atomicAdd(&out[(size_t)tok * DM + col0 + lc], g * v);
                    }
                }
            }
        }
    }
}

extern "C" void kernel_launch(void* const* d_in, const int* in_sizes, int n_in,
                              void* d_out, int out_size, void* d_ws, size_t ws_size,
                              hipStream_t stream) {
    const float* x   = (const float*)d_in[0];
    const float* wrt = (const float*)d_in[1];
    const float* w1  = (const float*)d_in[2];
    const float* w2  = (const float*)d_in[3];
    float* out = (float*)d_out;

    char* ws = (char*)d_ws;
    size_t o = 0;
    auto alloc = [&](size_t bytes) { size_t r = o; o += (bytes + 255) & ~255UL; return r; };
    unsigned short* x_bf  = (unsigned short*)(ws + alloc((size_t)NT * DM * 2));
    unsigned short* w1_bf = (unsigned short*)(ws + alloc((size_t)NE * DF * DM * 2));
    unsigned short* w2_bf = (unsigned short*)(ws + alloc((size_t)NE * DM * DF * 2));
    unsigned short* h_bf  = (unsigned short*)(ws + alloc((size_t)MAXROWS * DF * 2));
    int*   counts     = (int*)(ws + alloc(NE * 4));
    int*   offsets    = (int*)(ws + alloc(NE * 4));
    int*   token_list = (int*)(ws + alloc((size_t)NE * NT * 4));
    float* gate_list  = (float*)(ws + alloc((size_t)NE * NT * 4));

    hipMemsetAsync(counts, 0, NE * 4, stream);
    hipMemsetAsync(out, 0, (size_t)NT * DM * 4, stream);

    int n4x = NT * DM / 4;
    cast_kernel<<<(n4x + 255) / 256, 256, 0, stream>>>(x, x_bf, n4x);
    int n4w = NE * DF * DM / 4;
    cast_kernel<<<(n4w + 255) / 256, 256, 0, stream>>>(w1, w1_bf, n4w);
    cast_kernel<<<(n4w + 255) / 256, 256, 0, stream>>>(w2, w2_bf, n4w);

    router_kernel<<<NT / 4, 256, 0, stream>>>(x, wrt, counts, token_list, gate_list);
    scan_kernel<<<1, 64, 0, stream>>>(counts, offsets);

    // GEMM1: N=1024 -> 16 col tiles; rows: 8 experts x up to 128 row tiles
    moe_gemm<true><<<dim3(DF / 64, NT / 64, NE), 256, 0, stream>>>(
        x_bf, w1_bf, h_bf, nullptr, counts, offsets, token_list, gate_list);
    // GEMM2: N=512 -> 8 col tiles
    moe_gemm<false><<<dim3(DM / 64, NT / 64, NE), 256, 0, stream>>>(
        h_bf, w2_bf, nullptr, out, counts, offsets, token_list, gate_list);
}

// Round 2
// 174.419 us; speedup vs baseline: 1.9395x; 1.9395x over previous
//
#include <hip/hip_runtime.h>
#include <hip/hip_bf16.h>

#define NT 8192      // tokens
#define DM 512       // d_model
#define DF 1024      // d_ff
#define NE 8         // experts
#define MAXROWS (NT*2)

typedef __bf16 bf16_8 __attribute__((ext_vector_type(8)));
typedef float  f32_4  __attribute__((ext_vector_type(4)));
typedef unsigned short us8 __attribute__((ext_vector_type(8)));

__device__ inline unsigned short f2bf(float f) {
    unsigned int u = __float_as_uint(f);
    u = u + 0x7fffu + ((u >> 16) & 1u);   // RNE
    return (unsigned short)(u >> 16);
}

__device__ inline bf16_8 as_bf(us8 v) { return __builtin_bit_cast(bf16_8, v); }

// ---------------- cast f32 -> bf16 (4 elems/thread) ----------------
__global__ __launch_bounds__(256) void cast_kernel(const float* __restrict__ in,
                                                   unsigned short* __restrict__ out,
                                                   int n4) {
    int i = blockIdx.x * 256 + threadIdx.x;
    if (i >= n4) return;
    float4 v = ((const float4*)in)[i];
    ushort4 o;
    o.x = f2bf(v.x); o.y = f2bf(v.y); o.z = f2bf(v.z); o.w = f2bf(v.w);
    ((ushort4*)out)[i] = o;
}

// ---------------- router phase A: f32 logits, top-2, gates (NO atomics) ----------------
__global__ __launch_bounds__(256) void router_kernel(const float* __restrict__ x,
                                                     const float* __restrict__ wr,
                                                     int* __restrict__ eidx,
                                                     float2* __restrict__ gates) {
    const int wid = threadIdx.x >> 6;
    const int lane = threadIdx.x & 63;
    const int t = blockIdx.x * 4 + wid;

    const float4* xrow = (const float4*)(x + (size_t)t * DM);
    float4 xv0 = xrow[lane * 2];
    float4 xv1 = xrow[lane * 2 + 1];

    float logit[NE];
#pragma unroll
    for (int e = 0; e < NE; ++e) {
        const float4* wrow = (const float4*)(wr + (size_t)e * DM);
        float4 w0 = wrow[lane * 2];
        float4 w1v = wrow[lane * 2 + 1];
        float s = xv0.x * w0.x + xv0.y * w0.y + xv0.z * w0.z + xv0.w * w0.w
                + xv1.x * w1v.x + xv1.y * w1v.y + xv1.z * w1v.z + xv1.w * w1v.w;
#pragma unroll
        for (int off = 32; off >= 1; off >>= 1) s += __shfl_xor(s, off);
        logit[e] = s;
    }

    if (lane == 0) {
        int i0 = 0; float m0 = logit[0];
#pragma unroll
        for (int e = 1; e < NE; ++e) if (logit[e] > m0) { m0 = logit[e]; i0 = e; }
        int i1 = -1; float m1 = -1e30f;
#pragma unroll
        for (int e = 0; e < NE; ++e) if (e != i0 && logit[e] > m1) { m1 = logit[e]; i1 = e; }
        // gates: renormalized top-2 of softmax == 2-way softmax over (m0, m1)
        float d = expf(m1 - m0);
        float g0 = 1.0f / (1.0f + d);
        float g1 = 1.0f - g0;
        eidx[t] = i0 | (i1 << 8);
        gates[t] = make_float2(g0, g1);
    }
}

// ---------------- phase B: deterministic expert-list build (8 blocks, 1/expert) ----------------
__global__ __launch_bounds__(256) void build_lists_kernel(const int* __restrict__ eidx,
                                                          const float2* __restrict__ gates,
                                                          int* __restrict__ counts,
                                                          int* __restrict__ token_list,
                                                          float* __restrict__ gate_list) {
    const int e = blockIdx.x;
    const int tid = threadIdx.x;
    const int wid = tid >> 6, lane = tid & 63;
    __shared__ int wsum[4];
    __shared__ int base;
    if (tid == 0) base = 0;
    __syncthreads();
    for (int c = 0; c < NT; c += 256) {
        int t = c + tid;
        int ei = eidx[t];
        int i0 = ei & 0xff, i1 = (ei >> 8) & 0xff;
        bool match0 = (i0 == e), match1 = (i1 == e);
        bool m = match0 || match1;
        unsigned long long mask = __ballot(m);
        if (lane == 0) wsum[wid] = __popcll(mask);
        __syncthreads();
        int pre = 0;
#pragma unroll
        for (int w = 0; w < 4; ++w) if (w < wid) pre += wsum[w];
        int tot = wsum[0] + wsum[1] + wsum[2] + wsum[3];
        if (m) {
            int pos = base + pre + __popcll(mask & ((1ULL << lane) - 1ULL));
            token_list[e * NT + pos] = t;
            float2 g = gates[t];
            gate_list[e * NT + pos] = match0 ? g.x : g.y;
        }
        __syncthreads();
        if (tid == 0) base += tot;
        __syncthreads();
    }
    if (tid == 0) counts[e] = base;
}

// ---------------- exclusive scan over 8 counts ----------------
__global__ void scan_kernel(const int* __restrict__ counts, int* __restrict__ offsets) {
    if (threadIdx.x == 0) {
        int s = 0;
        for (int e = 0; e < NE; ++e) { offsets[e] = s; s += counts[e]; }
    }
}

// ---------------- fused MoE GEMM (templated on layer) ----------------
// G1: h = silu(gather(x) @ W1[e]^T)   A=x_bf16 [NT][512], B=w1 [NE][1024][512], out h bf16
// G2: out += gate * (h @ W2[e]^T)     A=h [rows][1024],  B=w2 [NE][512][1024], atomicAdd f32
template <bool G1>
__global__ __launch_bounds__(256) void moe_gemm(const unsigned short* __restrict__ Abase,
                                                const unsigned short* __restrict__ Wbase,
                                                unsigned short* __restrict__ h_out,
                                                float* __restrict__ out,
                                                const int* __restrict__ counts,
                                                const int* __restrict__ offsets,
                                                const int* __restrict__ token_list,
                                                const float* __restrict__ gate_list) {
    constexpr int K = G1 ? DM : DF;       // 512 : 1024
    constexpr int NCOLS = G1 ? DF : DM;   // 1024 : 512
    const int e = blockIdx.z;
    const int cnt = counts[e];
    const int row0 = blockIdx.y * 64;
    if (row0 >= cnt) return;
    const int col0 = blockIdx.x * 64;

    __shared__ __align__(16) unsigned short Alds[64][40];
    __shared__ __align__(16) unsigned short Blds[64][40];

    const int tr = threadIdx.x >> 2;   // 0..63 staged row
    const int tc = threadIdx.x & 3;    // 0..3  16B chunk within 32-wide K-step

    // per-thread A row pointer (fixed across K loop), clamped for tail tiles
    int rloc = min(row0 + tr, cnt - 1);
    const unsigned short* Arow;
    if (G1) {
        int tok = token_list[e * NT + rloc];
        Arow = Abase + (size_t)tok * K;
    } else {
        Arow = Abase + (size_t)(offsets[e] + rloc) * K;
    }
    const unsigned short* Brow = Wbase + ((size_t)e * NCOLS + (col0 + tr)) * K;

    const int wid = threadIdx.x >> 6;
    const int lane = threadIdx.x & 63;
    const int wr = wid >> 1, wc = wid & 1;
    const int lrow = lane & 15;
    const int kc = lane >> 4;

    f32_4 acc[2][2];
#pragma unroll
    for (int m = 0; m < 2; ++m)
#pragma unroll
        for (int n = 0; n < 2; ++n) acc[m][n] = (f32_4){0.f, 0.f, 0.f, 0.f};

    for (int k0 = 0; k0 < K; k0 += 32) {
        us8 av = *(const us8*)(Arow + k0 + tc * 8);
        us8 bv = *(const us8*)(Brow + k0 + tc * 8);
        __syncthreads();
        *(us8*)&Alds[tr][tc * 8] = av;
        *(us8*)&Blds[tr][tc * 8] = bv;
        __syncthreads();

        bf16_8 a[2], b[2];
#pragma unroll
        for (int m = 0; m < 2; ++m)
            a[m] = as_bf(*(const us8*)&Alds[wr * 32 + m * 16 + lrow][kc * 8]);
#pragma unroll
        for (int n = 0; n < 2; ++n)
            b[n] = as_bf(*(const us8*)&Blds[wc * 32 + n * 16 + lrow][kc * 8]);
#pragma unroll
        for (int m = 0; m < 2; ++m)
#pragma unroll
            for (int n = 0; n < 2; ++n)
                acc[m][n] = __builtin_amdgcn_mfma_f32_16x16x32_bf16(a[m], b[n], acc[m][n], 0, 0, 0);
    }

    // epilogue: D row = (lane>>4)*4 + q, col = lane&15 within each 16x16 frag
#pragma unroll
    for (int m = 0; m < 2; ++m) {
#pragma unroll
        for (int n = 0; n < 2; ++n) {
#pragma unroll
            for (int q = 0; q < 4; ++q) {
                int lr = wr * 32 + m * 16 + (lane >> 4) * 4 + q;
                int lc = wc * 32 + n * 16 + (lane & 15);
                int r = row0 + lr;
                if (r < cnt) {
                    float v = acc[m][n][q];
                    if (G1) {
                        v = v / (1.0f + expf(-v));  // silu
                        h_out[(size_t)(offsets[e] + r) * DF + col0 + lc] = f2bf(v);
                    } else {
                        float g = gate_list[e * NT + r];
                        int tok = token_list[e * NT + r];
                        atomicAdd(&out[(size_t)tok * DM + col0 + lc], g * v);
                    }
                }
            }
        }
    }
}

extern "C" void kernel_launch(void* const* d_in, const int* in_sizes, int n_in,
                              void* d_out, int out_size, void* d_ws, size_t ws_size,
                              hipStream_t stream) {
    const float* x   = (const float*)d_in[0];
    const float* wrt = (const float*)d_in[1];
    const float* w1  = (const float*)d_in[2];
    const float* w2  = (const float*)d_in[3];
    float* out = (float*)d_out;

    char* ws = (char*)d_ws;
    size_t o = 0;
    auto alloc = [&](size_t bytes) { size_t r = o; o += (bytes + 255) & ~255UL; return r; };
    unsigned short* x_bf  = (unsigned short*)(ws + alloc((size_t)NT * DM * 2));
    unsigned short* w1_bf = (unsigned short*)(ws + alloc((size_t)NE * DF * DM * 2));
    unsigned short* w2_bf = (unsigned short*)(ws + alloc((size_t)NE * DM * DF * 2));
    unsigned short* h_bf  = (unsigned short*)(ws + alloc((size_t)MAXROWS * DF * 2));
    int*   counts     = (int*)(ws + alloc(NE * 4));
    int*   offsets    = (int*)(ws + alloc(NE * 4));
    int*   token_list = (int*)(ws + alloc((size_t)NE * NT * 4));
    float* gate_list  = (float*)(ws + alloc((size_t)NE * NT * 4));
    int*   eidx       = (int*)(ws + alloc((size_t)NT * 4));
    float2* gates     = (float2*)(ws + alloc((size_t)NT * 8));

    hipMemsetAsync(out, 0, (size_t)NT * DM * 4, stream);

    int n4x = NT * DM / 4;
    cast_kernel<<<(n4x + 255) / 256, 256, 0, stream>>>(x, x_bf, n4x);
    int n4w = NE * DF * DM / 4;
    cast_kernel<<<(n4w + 255) / 256, 256, 0, stream>>>(w1, w1_bf, n4w);
    cast_kernel<<<(n4w + 255) / 256, 256, 0, stream>>>(w2, w2_bf, n4w);

    router_kernel<<<NT / 4, 256, 0, stream>>>(x, wrt, eidx, gates);
    build_lists_kernel<<<NE, 256, 0, stream>>>(eidx, gates, counts, token_list, gate_list);
    scan_kernel<<<1, 64, 0, stream>>>(counts, offsets);

    // GEMM1: N=1024 -> 16 col tiles; rows: 8 experts x up to 128 row tiles
    moe_gemm<true><<<dim3(DF / 64, NT / 64, NE), 256, 0, stream>>>(
        x_bf, w1_bf, h_bf, nullptr, counts, offsets, token_list, gate_list);
    // GEMM2: N=512 -> 8 col tiles
    moe_gemm<false><<<dim3(DM / 64, NT / 64, NE), 256, 0, stream>>>(
        h_bf, w2_bf, nullptr, out, counts, offsets, token_list, gate_list);
}

// Round 3
// 164.544 us; speedup vs baseline: 2.0558x; 1.0600x over previous
//
#include <hip/hip_runtime.h>
#include <hip/hip_bf16.h>

#define NT 8192      // tokens
#define DM 512       // d_model
#define DF 1024      // d_ff
#define NE 8         // experts
#define MAXROWS (NT*2)

typedef __bf16 bf16_8 __attribute__((ext_vector_type(8)));
typedef float  f32_4  __attribute__((ext_vector_type(4)));
typedef unsigned short us8 __attribute__((ext_vector_type(8)));

__device__ inline unsigned short f2bf(float f) {
    unsigned int u = __float_as_uint(f);
    u = u + 0x7fffu + ((u >> 16) & 1u);   // RNE
    return (unsigned short)(u >> 16);
}

__device__ inline bf16_8 as_bf(us8 v) { return __builtin_bit_cast(bf16_8, v); }

// async global -> LDS, 16B per lane (lane i lands at ldsbase + i*16)
__device__ inline void gld16(const unsigned short* g, unsigned short* l) {
    __builtin_amdgcn_global_load_lds(
        (const __attribute__((address_space(1))) unsigned int*)g,
        (__attribute__((address_space(3))) unsigned int*)l, 16, 0, 0);
}

// ---------------- cast f32 -> bf16 (4 elems/thread) ----------------
__global__ __launch_bounds__(256) void cast_kernel(const float* __restrict__ in,
                                                   unsigned short* __restrict__ out,
                                                   int n4) {
    int i = blockIdx.x * 256 + threadIdx.x;
    if (i >= n4) return;
    float4 v = ((const float4*)in)[i];
    ushort4 o;
    o.x = f2bf(v.x); o.y = f2bf(v.y); o.z = f2bf(v.z); o.w = f2bf(v.w);
    ((ushort4*)out)[i] = o;
}

// ---------------- router phase A: f32 logits, top-2, gates (NO atomics) ----------------
__global__ __launch_bounds__(256) void router_kernel(const float* __restrict__ x,
                                                     const float* __restrict__ wr,
                                                     int* __restrict__ eidx,
                                                     float2* __restrict__ gates) {
    const int wid = threadIdx.x >> 6;
    const int lane = threadIdx.x & 63;
    const int t = blockIdx.x * 4 + wid;

    const float4* xrow = (const float4*)(x + (size_t)t * DM);
    float4 xv0 = xrow[lane * 2];
    float4 xv1 = xrow[lane * 2 + 1];

    float logit[NE];
#pragma unroll
    for (int e = 0; e < NE; ++e) {
        const float4* wrow = (const float4*)(wr + (size_t)e * DM);
        float4 w0 = wrow[lane * 2];
        float4 w1v = wrow[lane * 2 + 1];
        float s = xv0.x * w0.x + xv0.y * w0.y + xv0.z * w0.z + xv0.w * w0.w
                + xv1.x * w1v.x + xv1.y * w1v.y + xv1.z * w1v.z + xv1.w * w1v.w;
#pragma unroll
        for (int off = 32; off >= 1; off >>= 1) s += __shfl_xor(s, off);
        logit[e] = s;
    }

    if (lane == 0) {
        int i0 = 0; float m0 = logit[0];
#pragma unroll
        for (int e = 1; e < NE; ++e) if (logit[e] > m0) { m0 = logit[e]; i0 = e; }
        int i1 = -1; float m1 = -1e30f;
#pragma unroll
        for (int e = 0; e < NE; ++e) if (e != i0 && logit[e] > m1) { m1 = logit[e]; i1 = e; }
        float d = expf(m1 - m0);
        float g0 = 1.0f / (1.0f + d);
        float g1 = 1.0f - g0;
        eidx[t] = i0 | (i1 << 8);
        gates[t] = make_float2(g0, g1);
    }
}

// ---------------- phase B: deterministic expert-list build (8 blocks, 1/expert) ----------------
__global__ __launch_bounds__(256) void build_lists_kernel(const int* __restrict__ eidx,
                                                          const float2* __restrict__ gates,
                                                          int* __restrict__ counts,
                                                          int* __restrict__ token_list,
                                                          float* __restrict__ gate_list) {
    const int e = blockIdx.x;
    const int tid = threadIdx.x;
    const int wid = tid >> 6, lane = tid & 63;
    __shared__ int wsum[4];
    __shared__ int base;
    if (tid == 0) base = 0;
    __syncthreads();
    for (int c = 0; c < NT; c += 256) {
        int t = c + tid;
        int ei = eidx[t];
        int i0 = ei & 0xff, i1 = (ei >> 8) & 0xff;
        bool match0 = (i0 == e), match1 = (i1 == e);
        bool m = match0 || match1;
        unsigned long long mask = __ballot(m);
        if (lane == 0) wsum[wid] = __popcll(mask);
        __syncthreads();
        int pre = 0;
#pragma unroll
        for (int w = 0; w < 4; ++w) if (w < wid) pre += wsum[w];
        int tot = wsum[0] + wsum[1] + wsum[2] + wsum[3];
        if (m) {
            int pos = base + pre + __popcll(mask & ((1ULL << lane) - 1ULL));
            token_list[e * NT + pos] = t;
            float2 g = gates[t];
            gate_list[e * NT + pos] = match0 ? g.x : g.y;
        }
        __syncthreads();
        if (tid == 0) base += tot;
        __syncthreads();
    }
    if (tid == 0) counts[e] = base;
}

// ---------------- exclusive scan over 8 counts ----------------
__global__ void scan_kernel(const int* __restrict__ counts, int* __restrict__ offsets) {
    if (threadIdx.x == 0) {
        int s = 0;
        for (int e = 0; e < NE; ++e) { offsets[e] = s; s += counts[e]; }
    }
}

// ---------------- fused MoE GEMM, m97 structure: 128x128 tile, global_load_lds ----------------
// G1: h = silu(gather(x) @ W1[e]^T)   A=x_bf16 [NT][512], B=w1 [NE][1024][512], out h bf16
// G2: out += gate * (h @ W2[e]^T)     A=h [rows][1024],  B=w2 [NE][512][1024], atomicAdd f32
// LDS tiles [128][32] linear (global_load_lds needs contiguous dest); XOR quarter
// swizzle applied BOTH on the global source (qs = q^(row&3)) and the ds_read
// (kcs = kc^(row&3)) -> 4-way instead of 8-way bank conflict.
template <bool G1>
__global__ __launch_bounds__(256) void moe_gemm(const unsigned short* __restrict__ Abase,
                                                const unsigned short* __restrict__ Wbase,
                                                unsigned short* __restrict__ h_out,
                                                float* __restrict__ out,
                                                const int* __restrict__ counts,
                                                const int* __restrict__ offsets,
                                                const int* __restrict__ token_list,
                                                const float* __restrict__ gate_list) {
    constexpr int K = G1 ? DM : DF;       // 512 : 1024
    constexpr int NCOLS = G1 ? DF : DM;   // 1024 : 512
    const int e = blockIdx.z;
    const int cnt = counts[e];
    const int row0 = blockIdx.y * 128;
    if (row0 >= cnt) return;
    const int col0 = blockIdx.x * 128;
    const int off_e = offsets[e];

    __shared__ __align__(16) unsigned short Alds[128 * 32];
    __shared__ __align__(16) unsigned short Blds[128 * 32];

    const int tid = threadIdx.x;
    const int wid = tid >> 6;
    const int lane = tid & 63;

    // staging: 512 chunks of 16B per tile; chunk c = wid*128 + l*64 + lane
    const int c0 = wid * 128 + lane;
    const int c1 = c0 + 64;
    const int r0 = c0 >> 2, q0 = c0 & 3;
    const int r1 = c1 >> 2, q1 = c1 & 3;
    const int qs0 = q0 ^ (r0 & 3);
    const int qs1 = q1 ^ (r1 & 3);

    const unsigned short* gA0;
    const unsigned short* gA1;
    {
        int rr0 = min(row0 + r0, cnt - 1);
        int rr1 = min(row0 + r1, cnt - 1);
        if (G1) {
            gA0 = Abase + (size_t)token_list[e * NT + rr0] * K + qs0 * 8;
            gA1 = Abase + (size_t)token_list[e * NT + rr1] * K + qs1 * 8;
        } else {
            gA0 = Abase + (size_t)(off_e + rr0) * K + qs0 * 8;
            gA1 = Abase + (size_t)(off_e + rr1) * K + qs1 * 8;
        }
    }
    const unsigned short* gB0 = Wbase + ((size_t)e * NCOLS + col0 + r0) * K + qs0 * 8;
    const unsigned short* gB1 = Wbase + ((size_t)e * NCOLS + col0 + r1) * K + qs1 * 8;

    unsigned short* ldsA0 = Alds + (wid * 128) * 8;
    unsigned short* ldsA1 = Alds + (wid * 128 + 64) * 8;
    unsigned short* ldsB0 = Blds + (wid * 128) * 8;
    unsigned short* ldsB1 = Blds + (wid * 128 + 64) * 8;

    // fragment read addresses (k0-independent; LDS rewritten each K-step)
    const int wr = wid >> 1, wc = wid & 1;
    const int lrow = lane & 15;
    const int kcs = (lane >> 4) ^ (lrow & 3);   // swizzled K-quarter
    const unsigned short* rdA[4];
    const unsigned short* rdB[4];
#pragma unroll
    for (int m = 0; m < 4; ++m)
        rdA[m] = Alds + (wr * 64 + m * 16 + lrow) * 32 + kcs * 8;
#pragma unroll
    for (int n = 0; n < 4; ++n)
        rdB[n] = Blds + (wc * 64 + n * 16 + lrow) * 32 + kcs * 8;

    f32_4 acc[4][4];
#pragma unroll
    for (int m = 0; m < 4; ++m)
#pragma unroll
        for (int n = 0; n < 4; ++n) acc[m][n] = (f32_4){0.f, 0.f, 0.f, 0.f};

    for (int k0 = 0; k0 < K; k0 += 32) {
        gld16(gA0 + k0, ldsA0);
        gld16(gA1 + k0, ldsA1);
        gld16(gB0 + k0, ldsB0);
        gld16(gB1 + k0, ldsB1);
        __syncthreads();   // drains vmcnt -> staging complete

        bf16_8 a[4], b[4];
#pragma unroll
        for (int m = 0; m < 4; ++m) a[m] = as_bf(*(const us8*)rdA[m]);
#pragma unroll
        for (int n = 0; n < 4; ++n) b[n] = as_bf(*(const us8*)rdB[n]);
#pragma unroll
        for (int m = 0; m < 4; ++m)
#pragma unroll
            for (int n = 0; n < 4; ++n)
                acc[m][n] = __builtin_amdgcn_mfma_f32_16x16x32_bf16(a[m], b[n], acc[m][n], 0, 0, 0);
        __syncthreads();   // all waves done reading before next overwrite
    }

    // epilogue: frag row = (lane>>4)*4 + q, col = lane&15
#pragma unroll
    for (int m = 0; m < 4; ++m) {
#pragma unroll
        for (int n = 0; n < 4; ++n) {
#pragma unroll
            for (int q = 0; q < 4; ++q) {
                int lr = wr * 64 + m * 16 + (lane >> 4) * 4 + q;
                int lc = wc * 64 + n * 16 + (lane & 15);
                int r = row0 + lr;
                if (r < cnt) {
                    float v = acc[m][n][q];
                    if (G1) {
                        v = v / (1.0f + expf(-v));  // silu
                        h_out[(size_t)(off_e + r) * DF + col0 + lc] = f2bf(v);
                    } else {
                        float g = gate_list[e * NT + r];
                        int tok = token_list[e * NT + r];
                        atomicAdd(&out[(size_t)tok * DM + col0 + lc], g * v);
                    }
                }
            }
        }
    }
}

extern "C" void kernel_launch(void* const* d_in, const int* in_sizes, int n_in,
                              void* d_out, int out_size, void* d_ws, size_t ws_size,
                              hipStream_t stream) {
    const float* x   = (const float*)d_in[0];
    const float* wrt = (const float*)d_in[1];
    const float* w1  = (const float*)d_in[2];
    const float* w2  = (const float*)d_in[3];
    float* out = (float*)d_out;

    char* ws = (char*)d_ws;
    size_t o = 0;
    auto alloc = [&](size_t bytes) { size_t r = o; o += (bytes + 255) & ~255UL; return r; };
    unsigned short* x_bf  = (unsigned short*)(ws + alloc((size_t)NT * DM * 2));
    unsigned short* w1_bf = (unsigned short*)(ws + alloc((size_t)NE * DF * DM * 2));
    unsigned short* w2_bf = (unsigned short*)(ws + alloc((size_t)NE * DM * DF * 2));
    unsigned short* h_bf  = (unsigned short*)(ws + alloc((size_t)MAXROWS * DF * 2));
    int*   counts     = (int*)(ws + alloc(NE * 4));
    int*   offsets    = (int*)(ws + alloc(NE * 4));
    int*   token_list = (int*)(ws + alloc((size_t)NE * NT * 4));
    float* gate_list  = (float*)(ws + alloc((size_t)NE * NT * 4));
    int*   eidx       = (int*)(ws + alloc((size_t)NT * 4));
    float2* gates     = (float2*)(ws + alloc((size_t)NT * 8));

    hipMemsetAsync(out, 0, (size_t)NT * DM * 4, stream);

    int n4x = NT * DM / 4;
    cast_kernel<<<(n4x + 255) / 256, 256, 0, stream>>>(x, x_bf, n4x);
    int n4w = NE * DF * DM / 4;
    cast_kernel<<<(n4w + 255) / 256, 256, 0, stream>>>(w1, w1_bf, n4w);
    cast_kernel<<<(n4w + 255) / 256, 256, 0, stream>>>(w2, w2_bf, n4w);

    router_kernel<<<NT / 4, 256, 0, stream>>>(x, wrt, eidx, gates);
    build_lists_kernel<<<NE, 256, 0, stream>>>(eidx, gates, counts, token_list, gate_list);
    scan_kernel<<<1, 64, 0, stream>>>(counts, offsets);

    // GEMM1: 1024 cols -> 8 col tiles; up to 64 row tiles per expert (cnt<=8192)
    moe_gemm<true><<<dim3(DF / 128, NT / 128, NE), 256, 0, stream>>>(
        x_bf, w1_bf, h_bf, nullptr, counts, offsets, token_list, gate_list);
    // GEMM2: 512 cols -> 4 col tiles
    moe_gemm<false><<<dim3(DM / 128, NT / 128, NE), 256, 0, stream>>>(
        h_bf, w2_bf, nullptr, out, counts, offsets, token_list, gate_list);
}